// Round 13
// baseline (324.083 us; speedup 1.0000x reference)
//
#include <hip/hip_runtime.h>
#include <hip/hip_bf16.h>

// Sizes fixed by the reference problem.
#define CN 32
#define RN 256
#define DN 512
#define NN 32
#define LN 256

// LDS layout of main kernel (bytes):
//  sAt   : bf16 [256][256] = 131072, 16B-chunk XOR swizzle (chunk ^= r&7)
//          Phase-C overlays live HERE (sAt dead then): w12s 8K @ +0,
//          nsqS 1K @ +8192, red @ +9216.
//  stage : 32768 = double-buffered staging (conS / Gs), 16K per buffer.
//          Freed after phase B -> next pair's con chunk-0 prefetch.
//  total : 163840 = 160 KiB (1 block/CU, 8 waves, 2 waves/SIMD; the 256-reg
//          per-wave budget is the binding occupancy limit -- R8/R10/R11)
#define STAGE_OFF 131072
#define SMEM_TOTAL 163840

typedef short v8s __attribute__((ext_vector_type(8)));
typedef float v4f __attribute__((ext_vector_type(4)));
typedef const __attribute__((address_space(1))) void* gas1_t;
typedef __attribute__((address_space(3))) void* las3_t;

__device__ __forceinline__ void gl2lds16(const void* g, void* l) {
  __builtin_amdgcn_global_load_lds((gas1_t)g, (las3_t)l, 16, 0, 0);
}

__device__ __forceinline__ unsigned short f2bf(float x) {
  unsigned int u = __float_as_uint(x);
  u = (u + 0x7fffu + ((u >> 16) & 1u)) >> 16;  // RNE
  return (unsigned short)u;
}
__device__ __forceinline__ float bf2f(unsigned short h) {
  return __uint_as_float(((unsigned int)h) << 16);
}

// Staging buffers ([256][32] shorts): 16B chunks XOR-swizzled with (r>>1)&3.
// Writes absorb the swizzle in the global fetch column; reads via this helper.
__device__ __forceinline__ const v8s* stgFrag(const unsigned short* buf, int r,
                                              int quad) {
  return (const v8s*)(buf + r * 32 + ((quad ^ ((r >> 1) & 3)) << 3));
}

// sAt addressing: row-major stride 256 shorts, 16B chunks XOR-swizzled by row.
__device__ __forceinline__ int satIdx(int r, int col) {
  return (r << 8) | ((((col >> 3) ^ (r & 7)) << 3) | (col & 7));
}

// Read an 8-float fragment from the fp32 gram slice (row-rotated by
// (quad+row)&3 in 8-float chunks) and convert to bf16x8.
__device__ __forceinline__ v8s ldFrag32(const float* buf, int r, int quad) {
  const float* p = buf + r * 32 + (((quad + r) & 3) << 3);
  const float4 x0 = ((const float4*)p)[0];
  const float4 x1 = ((const float4*)p)[1];
  unsigned short h[8];
  h[0] = f2bf(x0.x); h[1] = f2bf(x0.y); h[2] = f2bf(x0.z); h[3] = f2bf(x0.w);
  h[4] = f2bf(x1.x); h[5] = f2bf(x1.y); h[6] = f2bf(x1.z); h[7] = f2bf(x1.w);
  return *(v8s*)h;
}

// ---------------------------------------------------------------------------
// Fused setup (ONE launch, 512 threads/block, role by blockIdx):
//  blocks 0..255    : Gram G[n] = laws[n]@laws[n]^T (bf16 out), fp32 laws
//                     staged through LDS via gl2lds.
//  blocks 256..1279 : contracts fp32->bf16 (8 rows each) + row norms.
//  blocks 1280..2303: laws fp32->bf16 (4096 elements each).
// ---------------------------------------------------------------------------
__global__ __launch_bounds__(512) void setup_kernel(
    const float* __restrict__ con, const float* __restrict__ laws,
    unsigned short* __restrict__ lawsB, unsigned short* __restrict__ conB,
    float* __restrict__ cnorm, unsigned short* __restrict__ G) {
  const int bid = blockIdx.x;
  const int t = threadIdx.x;
  if (bid < 256) {
    __shared__ float slice[256 * 32];  // 32 KB fp32, row-rotated chunks
    const int n = bid >> 3;
    const int m0 = (bid & 7) << 5;  // 32-row output stripe
    const int lane = t & 63;
    const int w = t >> 6;
    const int quad = lane >> 4;
    const int l16 = lane & 15;
    const int rg = w >> 2;  // 0..1
    const int cg = w & 3;   // 0..3
    const float* lawN = laws + n * (LN * DN);
    const int srow = t >> 3;
    const int sc4 = (t >> 1) & 3;
    const int shalf = t & 1;

    v4f acc[4];
#pragma unroll
    for (int b = 0; b < 4; ++b) acc[b] = (v4f){0.f, 0.f, 0.f, 0.f};

    for (int ch = 0; ch < 16; ++ch) {
      const int dk = ch << 5;
      __syncthreads();
#pragma unroll
      for (int i = 0; i < 4; ++i) {
        const int row = i * 64 + srow;
        const int srcCol = (((sc4 - row) & 3) << 3) + (shalf << 2);
        gl2lds16(lawN + row * DN + dk + srcCol,
                 (char*)slice + i * 8192 + t * 16);
      }
      __syncthreads();
      v8s af = ldFrag32(slice, m0 + rg * 16 + l16, quad);
#pragma unroll
      for (int ct = 0; ct < 4; ++ct) {
        v8s bf = ldFrag32(slice, cg * 64 + ct * 16 + l16, quad);
        acc[ct] = __builtin_amdgcn_mfma_f32_16x16x32_bf16(af, bf, acc[ct], 0, 0, 0);
      }
    }
    unsigned short* g = G + n * (LN * LN);
#pragma unroll
    for (int ct = 0; ct < 4; ++ct)
#pragma unroll
      for (int reg = 0; reg < 4; ++reg) {
        const int l = m0 + rg * 16 + quad * 4 + reg;
        g[l * LN + cg * 64 + ct * 16 + l16] = f2bf(acc[ct][reg]);
      }
  } else if (bid < 1280) {
    const int r = (bid - 256) * 8 + (t >> 6);
    const int lane = t & 63;
    const float4* src = (const float4*)(con + r * DN + lane * 8);
    float4 x0 = src[0], x1 = src[1];
    unsigned short h[8];
    h[0] = f2bf(x0.x); h[1] = f2bf(x0.y); h[2] = f2bf(x0.z); h[3] = f2bf(x0.w);
    h[4] = f2bf(x1.x); h[5] = f2bf(x1.y); h[6] = f2bf(x1.z); h[7] = f2bf(x1.w);
    *(v8s*)(conB + r * DN + lane * 8) = *(v8s*)h;
    float s = x0.x * x0.x + x0.y * x0.y + x0.z * x0.z + x0.w * x0.w +
              x1.x * x1.x + x1.y * x1.y + x1.z * x1.z + x1.w * x1.w;
#pragma unroll
    for (int m = 1; m < 64; m <<= 1) s += __shfl_xor(s, m, 64);
    if (lane == 0) cnorm[r] = sqrtf(s);
  } else {
    const int off = (bid - 1280) * 4096 + t * 8;
    const float4* src = (const float4*)(laws + off);
    float4 x0 = src[0], x1 = src[1];
    unsigned short h[8];
    h[0] = f2bf(x0.x); h[1] = f2bf(x0.y); h[2] = f2bf(x0.z); h[3] = f2bf(x0.w);
    h[4] = f2bf(x1.x); h[5] = f2bf(x1.y); h[6] = f2bf(x1.z); h[7] = f2bf(x1.w);
    *(v8s*)(lawsB + off) = *(v8s*)h;
  }
}

// ---------------------------------------------------------------------------
// Persistent main: 256 blocks (1/CU), each processes 4 (n,c) pairs sharing
// one n (laws/G hot in L2/L1; A-frag pointers & nCh hoisted). Per pair the
// R12-proven phase structure; cross-pair pipelining: phase-C overlays live
// in the dead sAt region, freeing the stage buffers so the NEXT pair's con
// chunk-0 staging issues before phase C (epilogue hides staging latency; no
// inter-round dispatch drains).
// ---------------------------------------------------------------------------
__global__ __launch_bounds__(512, 2) void main_kernel(
    const int* __restrict__ law_lens, const unsigned short* __restrict__ lawsB,
    const unsigned short* __restrict__ conB, const unsigned short* __restrict__ Gm,
    const float* __restrict__ cnorm, float* __restrict__ out) {
  extern __shared__ char smem[];
  unsigned short* sAt = (unsigned short*)smem;  // [256][256] swizzled
  char* stage = smem + STAGE_OFF;               // 2 x 16K buffers

  const int bid = blockIdx.x;   // 0..255
  const int n = bid >> 3;       // 8 blocks per n
  const int c0 = (bid & 7) << 2;
  const int t = threadIdx.x;
  const int lane = t & 63;
  const int w = t >> 6;  // wave 0..7
  const int quad = lane >> 4;
  const int l16 = lane & 15;
  const int sub = t & 3;
  const int rQ = t >> 2;                   // 0..127
  const int subx = sub ^ ((rQ >> 1) & 3);  // swizzled source chunk
  const int len = law_lens[n];
  const int nCh = (len + 31) >> 5;         // phase-B k-chunks (block-uniform)

  const unsigned short* lawN = lawsB + n * (LN * DN);
  const unsigned short* Gn = Gm + n * (LN * LN);
  const unsigned short* a0p = lawN + (w * 32 + l16) * DN + quad * 8;
  const unsigned short* a1p = a0p + 16 * DN;

  // Phase-C overlays in the sAt region (dead by the time they're used).
  float* w12s = (float*)smem;           // [8][256] = 8K
  float* nsqS = (float*)(smem + 8192);  // [256]    = 1K
  float* red = (float*)(smem + 9216);   // [8]

  // Prologue: stage pair-0 con chunk 0 into buf0.
  {
    const unsigned short* conC = conB + c0 * (RN * DN);
#pragma unroll
    for (int i = 0; i < 2; ++i)
      gl2lds16(conC + (i * 128 + rQ) * DN + subx * 8,
               stage + i * 8192 + t * 16);
  }

  for (int k = 0; k < 4; ++k) {
    const int c = c0 + k;
    const unsigned short* conC = conB + c * (RN * DN);

    float w12p[16];
#pragma unroll
    for (int i = 0; i < 16; ++i) w12p[i] = 0.f;

    // ---------------- Phase A ----------------
    {
      v4f acc[2][16];
#pragma unroll
      for (int a = 0; a < 2; ++a)
#pragma unroll
        for (int b = 0; b < 16; ++b) acc[a][b] = (v4f){0.f, 0.f, 0.f, 0.f};

      for (int ch = 0; ch < 16; ++ch) {
        const int dk = ch << 5;
        __syncthreads();  // drains chunk-ch staging (issued in iter ch-1)
        v8s af0 = *(const v8s*)(a0p + dk);  // A-frags older than prefetch
        v8s af1 = *(const v8s*)(a1p + dk);
        __builtin_amdgcn_sched_barrier(0);
        if (ch < 15) {  // prefetch chunk ch+1 into the other buffer
          char* dst = stage + ((ch + 1) & 1) * 16384;
#pragma unroll
          for (int i = 0; i < 2; ++i)
            gl2lds16(conC + (i * 128 + rQ) * DN + (dk + 32) + subx * 8,
                     dst + i * 8192 + t * 16);
        }
        __builtin_amdgcn_sched_barrier(0);
        const unsigned short* cs =
            (const unsigned short*)(stage + (ch & 1) * 16384);
#pragma unroll
        for (int rt = 0; rt < 16; ++rt) {
          v8s bf = *stgFrag(cs, rt * 16 + l16, quad);
          acc[0][rt] = __builtin_amdgcn_mfma_f32_16x16x32_bf16(af0, bf, acc[0][rt], 0, 0, 0);
          acc[1][rt] = __builtin_amdgcn_mfma_f32_16x16x32_bf16(af1, bf, acc[1][rt], 0, 0, 0);
        }
      }
      // Softmax row ops -> sAt (packed b64 writes); w12 partials in regs.
#pragma unroll
      for (int tl = 0; tl < 2; ++tl) {
        unsigned int pk[16][2];
#pragma unroll
        for (int reg = 0; reg < 4; ++reg) {
          const int lg = w * 32 + tl * 16 + quad * 4 + reg;
          float v[16], lv[16];
          float ss = 0.f;
#pragma unroll
          for (int rt = 0; rt < 16; ++rt) {
            v[rt] = acc[tl][rt][reg] * 0.04419417382415922f;  // 1/sqrt(512)
            lv[rt] = v[rt] > 0.f ? v[rt] : 0.1f * v[rt];
            ss += lv[rt] * lv[rt];
          }
#pragma unroll
          for (int m = 1; m < 16; m <<= 1) ss += __shfl_xor(ss, m, 64);
          const float inv = 1.f / (sqrtf(ss) + 1e-8f);
          float e[16];
          float den = 0.f;
#pragma unroll
          for (int rt = 0; rt < 16; ++rt) {
            e[rt] = __expf(lv[rt] * inv);  // |lv*inv| <= 1, no max needed
            den += e[rt];
          }
#pragma unroll
          for (int m = 1; m < 16; m <<= 1) den += __shfl_xor(den, m, 64);
          const float sc = (lg < len) ? 4.f / den : 0.f;  // SMOOTH, masked
#pragma unroll
          for (int rt = 0; rt < 16; ++rt) {
            const float a = e[rt] * sc;
            w12p[rt] += a * v[rt];  // raw S -> cosine numerator
            const unsigned int h = f2bf(a);
            if (reg & 1)
              pk[rt][reg >> 1] |= h << 16;
            else
              pk[rt][reg >> 1] = h;
          }
        }
        const int lg0 = w * 32 + tl * 16 + quad * 4;
#pragma unroll
        for (int rt = 0; rt < 16; ++rt)
          *(uint2*)(sAt + satIdx(rt * 16 + l16, lg0)) = *(uint2*)pk[rt];
      }
    }

    __syncthreads();  // sAt writes done (all waves); conS reads done

    // Prologue: stage G chunk 0 into buf0 (overlaps w12 shuffles below).
#pragma unroll
    for (int i = 0; i < 2; ++i)
      gl2lds16(Gn + (i * 128 + rQ) * LN + subx * 8, stage + i * 8192 + t * 16);

    // Reduce w12 partials across quads; keep in registers through phase B.
#pragma unroll
    for (int rt = 0; rt < 16; ++rt) {
      w12p[rt] += __shfl_xor(w12p[rt], 16, 64);
      w12p[rt] += __shfl_xor(w12p[rt], 32, 64);
    }

    // ---------------- Phase B (k capped at nCh = ceil(len/32)) --------------
    float nsv[2][4];
    {
      v4f acc[2][16];
#pragma unroll
      for (int a = 0; a < 2; ++a)
#pragma unroll
        for (int b = 0; b < 16; ++b) acc[a][b] = (v4f){0.f, 0.f, 0.f, 0.f};

      for (int ch = 0; ch < nCh; ++ch) {
        const int lk = ch << 5;
        __syncthreads();  // drains chunk-ch Gs staging
        v8s af0 = *(const v8s*)(sAt + satIdx(w * 32 + l16, lk + quad * 8));
        v8s af1 = *(const v8s*)(sAt + satIdx(w * 32 + 16 + l16, lk + quad * 8));
        __builtin_amdgcn_sched_barrier(0);
        if (ch < nCh - 1) {  // prefetch chunk ch+1
          char* dst = stage + ((ch + 1) & 1) * 16384;
#pragma unroll
          for (int i = 0; i < 2; ++i)
            gl2lds16(Gn + (i * 128 + rQ) * LN + (lk + 32) + subx * 8,
                     dst + i * 8192 + t * 16);
        }
        __builtin_amdgcn_sched_barrier(0);
        const unsigned short* gs =
            (const unsigned short*)(stage + (ch & 1) * 16384);
#pragma unroll
        for (int lt = 0; lt < 16; ++lt) {
          v8s bf = *stgFrag(gs, lt * 16 + l16, quad);  // G row (symmetric)
          acc[0][lt] = __builtin_amdgcn_mfma_f32_16x16x32_bf16(af0, bf, acc[0][lt], 0, 0, 0);
          acc[1][lt] = __builtin_amdgcn_mfma_f32_16x16x32_bf16(af1, bf, acc[1][lt], 0, 0, 0);
        }
      }
      // nsq[r] = sum_l At[r,l] * U[r,l] (reads sAt + registers only)
#pragma unroll
      for (int tl = 0; tl < 2; ++tl) {
#pragma unroll
        for (int reg = 0; reg < 4; ++reg) {
          const int r = w * 32 + tl * 16 + quad * 4 + reg;
          float s = 0.f;
#pragma unroll
          for (int lt = 0; lt < 16; ++lt)
            s += acc[tl][lt][reg] * bf2f(sAt[satIdx(r, lt * 16 + l16)]);
#pragma unroll
          for (int m = 1; m < 16; m <<= 1) s += __shfl_xor(s, m, 64);
          nsv[tl][reg] = s;
        }
      }
    }

    __syncthreads();  // all Gs + sAt reads done; stage & sAt regions free

    // Prefetch NEXT pair's con chunk 0 into buf0 (hidden under phase C).
    if (k < 3) {
      const unsigned short* conN = conB + (c + 1) * (RN * DN);
#pragma unroll
      for (int i = 0; i < 2; ++i)
        gl2lds16(conN + (i * 128 + rQ) * DN + subx * 8,
                 stage + i * 8192 + t * 16);
    }

    // ---------------- Phase C (overlays in sAt region) ----------------
    if (l16 == 0) {
#pragma unroll
      for (int tl = 0; tl < 2; ++tl)
#pragma unroll
        for (int reg = 0; reg < 4; ++reg)
          nsqS[w * 32 + tl * 16 + quad * 4 + reg] = nsv[tl][reg];
    }
    if (lane < 16) {
#pragma unroll
      for (int rt = 0; rt < 16; ++rt) w12s[w * 256 + rt * 16 + lane] = w12p[rt];
    }
    __syncthreads();
    float p = 0.f;
    if (t < 256) {
      float w12 = 0.f;
#pragma unroll
      for (int i = 0; i < 8; ++i) w12 += w12s[i * 256 + t];
      const float w1 = cnorm[c * RN + t];
      const float w2 = sqrtf(fmaxf(nsqS[t], 0.f));
      const float sim = (w12 * 22.627416997969522f) / fmaxf(w1 * w2, 1e-8f);
      p = __expf(6.f * sim);
    }
#pragma unroll
    for (int m = 1; m < 64; m <<= 1) p += __shfl_xor(p, m, 64);
    if (lane == 0) red[w] = p;
    __syncthreads();
    if (t == 0) {
      float s = 0.f;
#pragma unroll
      for (int i = 0; i < 8; ++i) s += red[i];
      out[c * NN + n] = logf(s) / 6.f;
    }
    // Next pair's phase A rejoins at its first __syncthreads(); overlay
    // region (sAt rows 0..17) is only rewritten in its softmax pass, far
    // behind many barriers.
  }
}

// ---------------------------------------------------------------------------
extern "C" void kernel_launch(void* const* d_in, const int* in_sizes, int n_in,
                              void* d_out, int out_size, void* d_ws, size_t ws_size,
                              hipStream_t stream) {
  (void)in_sizes; (void)n_in; (void)out_size;
  const float* contracts = (const float*)d_in[0];
  const float* laws = (const float*)d_in[1];
  const int* law_lens = (const int*)d_in[2];
  float* out = (float*)d_out;

  // Workspace layout (21,004,288 B total)
  unsigned short* lawsB = (unsigned short*)d_ws;  // 8 MiB
  unsigned short* conB = lawsB + NN * LN * DN;    // 8 MiB
  unsigned short* G = conB + CN * RN * DN;        // 4 MiB
  float* cnorm = (float*)(G + NN * LN * LN);      // 32 KiB
  if (ws_size < (size_t)21004288) return;

  hipFuncSetAttribute((const void*)main_kernel,
                      hipFuncAttributeMaxDynamicSharedMemorySize, SMEM_TOTAL);

  // 256 gram + 1024 contracts-prep + 1024 laws-prep blocks, one launch.
  setup_kernel<<<2304, 512, 0, stream>>>(contracts, laws, lawsB, conB, cnorm,
                                         G);
  // Persistent: 256 blocks (1/CU), 4 same-n (n,c) pairs each.
  main_kernel<<<256, 512, SMEM_TOTAL, stream>>>(law_lens, lawsB, conB, G,
                                                cnorm, out);
}

// Round 14
// 248.138 us; speedup vs baseline: 1.3061x; 1.3061x over previous
//
#include <hip/hip_runtime.h>
#include <hip/hip_bf16.h>

// Sizes fixed by the reference problem.
#define CN 32
#define RN 256
#define DN 512
#define NN 32
#define LN 256

// LDS layout of main kernel (bytes):
//  sAt   : bf16 [256][256] = 131072, 16B-chunk XOR swizzle (chunk ^= r&7)
//  stage : 32768 = double-buffered staging (conS / Gs), 16K per buffer.
//          Epilogue reductions (w12s 8K, nsqS 1K, red) overlay this region.
//  total : 163840 = 160 KiB (1 block/CU, 8 waves, 2 waves/SIMD, 256-reg
//          budget; R8/R10/R11 proved bigger tiles spill at every occupancy;
//          R13 proved persistence thrashes per-XCD L2 -> keep 1024 blocks)
#define STAGE_OFF 131072
#define SMEM_TOTAL 163840

typedef short v8s __attribute__((ext_vector_type(8)));
typedef float v4f __attribute__((ext_vector_type(4)));
typedef const __attribute__((address_space(1))) void* gas1_t;
typedef __attribute__((address_space(3))) void* las3_t;

__device__ __forceinline__ void gl2lds16(const void* g, void* l) {
  __builtin_amdgcn_global_load_lds((gas1_t)g, (las3_t)l, 16, 0, 0);
}

__device__ __forceinline__ unsigned short f2bf(float x) {
  unsigned int u = __float_as_uint(x);
  u = (u + 0x7fffu + ((u >> 16) & 1u)) >> 16;  // RNE
  return (unsigned short)u;
}
__device__ __forceinline__ float bf2f(unsigned short h) {
  return __uint_as_float(((unsigned int)h) << 16);
}

// Staging buffers ([256][32] shorts): 16B chunks XOR-swizzled with (r>>1)&3.
// Writes absorb the swizzle in the global fetch column; reads via this helper.
__device__ __forceinline__ const v8s* stgFrag(const unsigned short* buf, int r,
                                              int quad) {
  return (const v8s*)(buf + r * 32 + ((quad ^ ((r >> 1) & 3)) << 3));
}

// sAt addressing: row-major stride 256 shorts, 16B chunks XOR-swizzled by row.
__device__ __forceinline__ int satIdx(int r, int col) {
  return (r << 8) | ((((col >> 3) ^ (r & 7)) << 3) | (col & 7));
}

// Read an 8-float fragment from the fp32 gram slice [256][64] (32B chunks
// rotated by row: chunk position cp holds source chunk (cp+row)&7) and
// convert to bf16x8. Bank check: 16 lanes (rows r..r+15), chunk (cp+r)&7
// cycles all 8 positions -> 2-way aliasing only (free, m136).
__device__ __forceinline__ v8s ldFrag64(const float* buf, int r, int cp) {
  const float* p = buf + r * 64 + (((cp + r) & 7) << 3);
  const float4 x0 = ((const float4*)p)[0];
  const float4 x1 = ((const float4*)p)[1];
  unsigned short h[8];
  h[0] = f2bf(x0.x); h[1] = f2bf(x0.y); h[2] = f2bf(x0.z); h[3] = f2bf(x0.w);
  h[4] = f2bf(x1.x); h[5] = f2bf(x1.y); h[6] = f2bf(x1.z); h[7] = f2bf(x1.w);
  return *(v8s*)h;
}

// ---------------------------------------------------------------------------
// Fused setup (ONE launch, 512 threads/block, role by blockIdx):
//  blocks 0..255    : Gram G[n] = laws[n]@laws[n]^T (bf16 out), fp32 laws
//                     staged through LDS via gl2lds. 64-wide K chunks ->
//                     8 chunk iterations (half the barrier drains of R12).
//  blocks 256..1279 : contracts fp32->bf16 (8 rows each) + row norms.
//  blocks 1280..2303: laws fp32->bf16 (4096 elements each).
// ---------------------------------------------------------------------------
__global__ __launch_bounds__(512) void setup_kernel(
    const float* __restrict__ con, const float* __restrict__ laws,
    unsigned short* __restrict__ lawsB, unsigned short* __restrict__ conB,
    float* __restrict__ cnorm, unsigned short* __restrict__ G) {
  const int bid = blockIdx.x;
  const int t = threadIdx.x;
  if (bid < 256) {
    __shared__ float slice[256 * 64];  // 64 KB fp32, row-rotated 32B chunks
    const int n = bid >> 3;
    const int m0 = (bid & 7) << 5;  // 32-row output stripe
    const int lane = t & 63;
    const int w = t >> 6;
    const int quad = lane >> 4;
    const int l16 = lane & 15;
    const int rg = w >> 2;  // 0..1
    const int cg = w & 3;   // 0..3
    const float* lawN = laws + n * (LN * DN);

    v4f acc[4];
#pragma unroll
    for (int b = 0; b < 4; ++b) acc[b] = (v4f){0.f, 0.f, 0.f, 0.f};

    for (int ch = 0; ch < 8; ++ch) {
      const int dk = ch << 6;
      __syncthreads();
      // Stage 256x64 floats: slot s = i*512+t -> (row = s>>4, piece p = s&15);
      // 16B piece p of the rotated row holds source chunk ((p>>1)-row)&7,
      // half p&1.
#pragma unroll
      for (int i = 0; i < 8; ++i) {
        const int s = i * 512 + t;
        const int row = s >> 4;
        const int p = s & 15;
        const int srcCol = ((((p >> 1) - row) & 7) << 3) + ((p & 1) << 2);
        gl2lds16(lawN + row * DN + dk + srcCol, (char*)slice + s * 16);
      }
      __syncthreads();
#pragma unroll
      for (int step = 0; step < 2; ++step) {
        const int cp = quad + (step << 2);
        v8s af = ldFrag64(slice, m0 + rg * 16 + l16, cp);
#pragma unroll
        for (int ct = 0; ct < 4; ++ct) {
          v8s bf = ldFrag64(slice, cg * 64 + ct * 16 + l16, cp);
          acc[ct] = __builtin_amdgcn_mfma_f32_16x16x32_bf16(af, bf, acc[ct], 0, 0, 0);
        }
      }
    }
    unsigned short* g = G + n * (LN * LN);
#pragma unroll
    for (int ct = 0; ct < 4; ++ct)
#pragma unroll
      for (int reg = 0; reg < 4; ++reg) {
        const int l = m0 + rg * 16 + quad * 4 + reg;
        g[l * LN + cg * 64 + ct * 16 + l16] = f2bf(acc[ct][reg]);
      }
  } else if (bid < 1280) {
    const int r = (bid - 256) * 8 + (t >> 6);
    const int lane = t & 63;
    const float4* src = (const float4*)(con + r * DN + lane * 8);
    float4 x0 = src[0], x1 = src[1];
    unsigned short h[8];
    h[0] = f2bf(x0.x); h[1] = f2bf(x0.y); h[2] = f2bf(x0.z); h[3] = f2bf(x0.w);
    h[4] = f2bf(x1.x); h[5] = f2bf(x1.y); h[6] = f2bf(x1.z); h[7] = f2bf(x1.w);
    *(v8s*)(conB + r * DN + lane * 8) = *(v8s*)h;
    float s = x0.x * x0.x + x0.y * x0.y + x0.z * x0.z + x0.w * x0.w +
              x1.x * x1.x + x1.y * x1.y + x1.z * x1.z + x1.w * x1.w;
#pragma unroll
    for (int m = 1; m < 64; m <<= 1) s += __shfl_xor(s, m, 64);
    if (lane == 0) cnorm[r] = sqrtf(s);
  } else {
    const int off = (bid - 1280) * 4096 + t * 8;
    const float4* src = (const float4*)(laws + off);
    float4 x0 = src[0], x1 = src[1];
    unsigned short h[8];
    h[0] = f2bf(x0.x); h[1] = f2bf(x0.y); h[2] = f2bf(x0.z); h[3] = f2bf(x0.w);
    h[4] = f2bf(x1.x); h[5] = f2bf(x1.y); h[6] = f2bf(x1.z); h[7] = f2bf(x1.w);
    *(v8s*)(lawsB + off) = *(v8s*)h;
  }
}

// ---------------------------------------------------------------------------
// Main: one block per (n,c), 512 threads (8 waves). R12-verbatim (best
// measured: 170.8 us, no spill).
// Phase A: S = laws[n]@con[c]^T; con staged via gl2lds dbuf (1 barrier per
//          chunk, prefetch overlaps compute); A-frags direct global;
//          softmax rows in-reg -> sAt bf16; w12 partials in registers.
// Phase B: U = At@G, G staged dbuf; k capped at nCh = ceil(len/32)
//          (block-uniform; At == 0 beyond len); nsq[r] = sum_l At[r,l]U[r,l].
// Phase C: sim = sqrt(D)*w12/(w1*w2); out[c,n] = LSE_6 over r.
// ---------------------------------------------------------------------------
__global__ __launch_bounds__(512, 2) void main_kernel(
    const int* __restrict__ law_lens, const unsigned short* __restrict__ lawsB,
    const unsigned short* __restrict__ conB, const unsigned short* __restrict__ Gm,
    const float* __restrict__ cnorm, float* __restrict__ out) {
  extern __shared__ char smem[];
  unsigned short* sAt = (unsigned short*)smem;  // [256][256] swizzled
  char* stage = smem + STAGE_OFF;               // 2 x 16K buffers

  const int bid = blockIdx.x;
  const int n = bid >> 5;  // 32 consecutive blocks share one n
  const int c = bid & 31;
  const int t = threadIdx.x;
  const int lane = t & 63;
  const int w = t >> 6;  // wave 0..7
  const int quad = lane >> 4;
  const int l16 = lane & 15;
  const int sub = t & 3;
  const int rQ = t >> 2;                   // 0..127
  const int subx = sub ^ ((rQ >> 1) & 3);  // swizzled source chunk
  const int len = law_lens[n];
  const int nCh = (len + 31) >> 5;         // phase-B k-chunks (block-uniform)

  const unsigned short* lawN = lawsB + n * (LN * DN);
  const unsigned short* conC = conB + c * (RN * DN);
  const unsigned short* Gn = Gm + n * (LN * LN);

  float w12p[16];
#pragma unroll
  for (int i = 0; i < 16; ++i) w12p[i] = 0.f;

  // ---------------- Phase A ----------------
  {
    const unsigned short* a0p = lawN + (w * 32 + l16) * DN + quad * 8;
    const unsigned short* a1p = a0p + 16 * DN;

    v4f acc[2][16];
#pragma unroll
    for (int a = 0; a < 2; ++a)
#pragma unroll
      for (int b = 0; b < 16; ++b) acc[a][b] = (v4f){0.f, 0.f, 0.f, 0.f};

    // Prologue: stage con chunk 0 into buf0.
#pragma unroll
    for (int i = 0; i < 2; ++i)
      gl2lds16(conC + (i * 128 + rQ) * DN + subx * 8,
               stage + i * 8192 + t * 16);

    for (int ch = 0; ch < 16; ++ch) {
      const int dk = ch << 5;
      __syncthreads();  // drains chunk-ch staging (in flight since iter ch-1)
      // A-frags FIRST (older than prefetch -> auto-wait becomes vmcnt(2)).
      v8s af0 = *(const v8s*)(a0p + dk);
      v8s af1 = *(const v8s*)(a1p + dk);
      __builtin_amdgcn_sched_barrier(0);
      if (ch < 15) {  // prefetch chunk ch+1 into the other buffer
        char* dst = stage + ((ch + 1) & 1) * 16384;
#pragma unroll
        for (int i = 0; i < 2; ++i)
          gl2lds16(conC + (i * 128 + rQ) * DN + (dk + 32) + subx * 8,
                   dst + i * 8192 + t * 16);
      }
      __builtin_amdgcn_sched_barrier(0);
      const unsigned short* cs =
          (const unsigned short*)(stage + (ch & 1) * 16384);
#pragma unroll
      for (int rt = 0; rt < 16; ++rt) {
        v8s bf = *stgFrag(cs, rt * 16 + l16, quad);
        acc[0][rt] = __builtin_amdgcn_mfma_f32_16x16x32_bf16(af0, bf, acc[0][rt], 0, 0, 0);
        acc[1][rt] = __builtin_amdgcn_mfma_f32_16x16x32_bf16(af1, bf, acc[1][rt], 0, 0, 0);
      }
    }
    // Row ops: row l lives in 16 lanes (C layout col=lane&15 -> r index).
    // 4 regs of a tile = 4 consecutive sAt columns -> packed b64 writes.
#pragma unroll
    for (int tl = 0; tl < 2; ++tl) {
      unsigned int pk[16][2];
#pragma unroll
      for (int reg = 0; reg < 4; ++reg) {
        const int lg = w * 32 + tl * 16 + quad * 4 + reg;
        float v[16], lv[16];
        float ss = 0.f;
#pragma unroll
        for (int rt = 0; rt < 16; ++rt) {
          v[rt] = acc[tl][rt][reg] * 0.04419417382415922f;  // 1/sqrt(512)
          lv[rt] = v[rt] > 0.f ? v[rt] : 0.1f * v[rt];
          ss += lv[rt] * lv[rt];
        }
#pragma unroll
        for (int m = 1; m < 16; m <<= 1) ss += __shfl_xor(ss, m, 64);
        const float inv = 1.f / (sqrtf(ss) + 1e-8f);
        float e[16];
        float den = 0.f;
#pragma unroll
        for (int rt = 0; rt < 16; ++rt) {
          e[rt] = __expf(lv[rt] * inv);  // |lv*inv| <= 1, no max needed
          den += e[rt];
        }
#pragma unroll
        for (int m = 1; m < 16; m <<= 1) den += __shfl_xor(den, m, 64);
        const float sc = (lg < len) ? 4.f / den : 0.f;  // SMOOTH, masked
#pragma unroll
        for (int rt = 0; rt < 16; ++rt) {
          const float a = e[rt] * sc;
          w12p[rt] += a * v[rt];  // raw S -> cosine numerator
          const unsigned int h = f2bf(a);
          if (reg & 1)
            pk[rt][reg >> 1] |= h << 16;
          else
            pk[rt][reg >> 1] = h;
        }
      }
      const int lg0 = w * 32 + tl * 16 + quad * 4;
#pragma unroll
      for (int rt = 0; rt < 16; ++rt)
        *(uint2*)(sAt + satIdx(rt * 16 + l16, lg0)) = *(uint2*)pk[rt];
    }
  }

  __syncthreads();  // sAt writes done (all waves); conS reads done

  // Prologue: stage G chunk 0 into buf0 (overlaps w12 shuffles below).
#pragma unroll
  for (int i = 0; i < 2; ++i)
    gl2lds16(Gn + (i * 128 + rQ) * LN + subx * 8, stage + i * 8192 + t * 16);

  // Reduce w12 partials across quads; keep in registers through phase B.
#pragma unroll
  for (int rt = 0; rt < 16; ++rt) {
    w12p[rt] += __shfl_xor(w12p[rt], 16, 64);
    w12p[rt] += __shfl_xor(w12p[rt], 32, 64);
  }

  // ---------------- Phase B (k capped at nCh = ceil(len/32)) ----------------
  float nsv[2][4];
  {
    v4f acc[2][16];
#pragma unroll
    for (int a = 0; a < 2; ++a)
#pragma unroll
      for (int b = 0; b < 16; ++b) acc[a][b] = (v4f){0.f, 0.f, 0.f, 0.f};

    for (int ch = 0; ch < nCh; ++ch) {
      const int lk = ch << 5;
      __syncthreads();  // drains chunk-ch Gs staging
      v8s af0 = *(const v8s*)(sAt + satIdx(w * 32 + l16, lk + quad * 8));
      v8s af1 = *(const v8s*)(sAt + satIdx(w * 32 + 16 + l16, lk + quad * 8));
      __builtin_amdgcn_sched_barrier(0);
      if (ch < nCh - 1) {  // prefetch chunk ch+1
        char* dst = stage + ((ch + 1) & 1) * 16384;
#pragma unroll
        for (int i = 0; i < 2; ++i)
          gl2lds16(Gn + (i * 128 + rQ) * LN + (lk + 32) + subx * 8,
                   dst + i * 8192 + t * 16);
      }
      __builtin_amdgcn_sched_barrier(0);
      const unsigned short* gs =
          (const unsigned short*)(stage + (ch & 1) * 16384);
#pragma unroll
      for (int lt = 0; lt < 16; ++lt) {
        v8s bf = *stgFrag(gs, lt * 16 + l16, quad);  // G row (symmetric)
        acc[0][lt] = __builtin_amdgcn_mfma_f32_16x16x32_bf16(af0, bf, acc[0][lt], 0, 0, 0);
        acc[1][lt] = __builtin_amdgcn_mfma_f32_16x16x32_bf16(af1, bf, acc[1][lt], 0, 0, 0);
      }
    }
    // nsq[r] = sum_l At[r,l] * U[r,l] (reads sAt + registers only)
#pragma unroll
    for (int tl = 0; tl < 2; ++tl) {
#pragma unroll
      for (int reg = 0; reg < 4; ++reg) {
        const int r = w * 32 + tl * 16 + quad * 4 + reg;
        float s = 0.f;
#pragma unroll
        for (int lt = 0; lt < 16; ++lt)
          s += acc[tl][lt][reg] * bf2f(sAt[satIdx(r, lt * 16 + l16)]);
#pragma unroll
        for (int m = 1; m < 16; m <<= 1) s += __shfl_xor(s, m, 64);
        nsv[tl][reg] = s;
      }
    }
  }

  // ---------------- Phase C (reductions overlay the stage region) ----------
  float* w12s = (float*)stage;           // [8][256] = 8K
  float* nsqS = (float*)(stage + 8192);  // [256]    = 1K
  float* red = (float*)(stage + 9216);   // [8]
  __syncthreads();  // all Gs reads done; stage is free for reductions
  if (l16 == 0) {
#pragma unroll
    for (int tl = 0; tl < 2; ++tl)
#pragma unroll
      for (int reg = 0; reg < 4; ++reg)
        nsqS[w * 32 + tl * 16 + quad * 4 + reg] = nsv[tl][reg];
  }
  if (lane < 16) {
#pragma unroll
    for (int rt = 0; rt < 16; ++rt) w12s[w * 256 + rt * 16 + lane] = w12p[rt];
  }
  __syncthreads();
  float p = 0.f;
  if (t < 256) {
    float w12 = 0.f;
#pragma unroll
    for (int i = 0; i < 8; ++i) w12 += w12s[i * 256 + t];
    const float w1 = cnorm[c * RN + t];
    const float w2 = sqrtf(fmaxf(nsqS[t], 0.f));
    const float sim = (w12 * 22.627416997969522f) / fmaxf(w1 * w2, 1e-8f);
    p = __expf(6.f * sim);
  }
#pragma unroll
  for (int m = 1; m < 64; m <<= 1) p += __shfl_xor(p, m, 64);
  if (lane == 0) red[w] = p;
  __syncthreads();
  if (t == 0) {
    float s = 0.f;
#pragma unroll
    for (int i = 0; i < 8; ++i) s += red[i];
    out[c * NN + n] = logf(s) / 6.f;
  }
}

// ---------------------------------------------------------------------------
extern "C" void kernel_launch(void* const* d_in, const int* in_sizes, int n_in,
                              void* d_out, int out_size, void* d_ws, size_t ws_size,
                              hipStream_t stream) {
  (void)in_sizes; (void)n_in; (void)out_size;
  const float* contracts = (const float*)d_in[0];
  const float* laws = (const float*)d_in[1];
  const int* law_lens = (const int*)d_in[2];
  float* out = (float*)d_out;

  // Workspace layout (21,004,288 B total)
  unsigned short* lawsB = (unsigned short*)d_ws;  // 8 MiB
  unsigned short* conB = lawsB + NN * LN * DN;    // 8 MiB
  unsigned short* G = conB + CN * RN * DN;        // 4 MiB
  float* cnorm = (float*)(G + NN * LN * LN);      // 32 KiB
  if (ws_size < (size_t)21004288) return;

  hipFuncSetAttribute((const void*)main_kernel,
                      hipFuncAttributeMaxDynamicSharedMemorySize, SMEM_TOTAL);

  // 256 gram + 1024 contracts-prep + 1024 laws-prep blocks, one launch.
  setup_kernel<<<2304, 512, 0, stream>>>(contracts, laws, lawsB, conB, cnorm,
                                         G);
  main_kernel<<<1024, 512, SMEM_TOTAL, stream>>>(law_lens, lawsB, conB, G,
                                                 cnorm, out);
}

// Round 15
// 244.382 us; speedup vs baseline: 1.3261x; 1.0154x over previous
//
#include <hip/hip_runtime.h>
#include <hip/hip_bf16.h>

// Sizes fixed by the reference problem.
#define CN 32
#define RN 256
#define DN 512
#define NN 32
#define LN 256

// LDS layout of main kernel (bytes):
//  sAt   : bf16 [256][256] = 131072, 16B-chunk XOR swizzle (chunk ^= r&7)
//  stage : 32768 = double-buffered staging (conS / Gs), 16K per buffer.
//          Epilogue reductions (w12s 8K, nsqS 1K, red) overlay this region.
//  total : 163840 = 160 KiB (1 block/CU, 8 waves, 2 waves/SIMD, 256-reg
//          budget; R8/R10/R11 proved bigger tiles spill at every occupancy;
//          R13 proved persistence thrashes per-XCD L2 -> keep 1024 blocks)
#define STAGE_OFF 131072
#define SMEM_TOTAL 163840

typedef short v8s __attribute__((ext_vector_type(8)));
typedef float v4f __attribute__((ext_vector_type(4)));
typedef const __attribute__((address_space(1))) void* gas1_t;
typedef __attribute__((address_space(3))) void* las3_t;

__device__ __forceinline__ void gl2lds16(const void* g, void* l) {
  __builtin_amdgcn_global_load_lds((gas1_t)g, (las3_t)l, 16, 0, 0);
}

__device__ __forceinline__ unsigned short f2bf(float x) {
  unsigned int u = __float_as_uint(x);
  u = (u + 0x7fffu + ((u >> 16) & 1u)) >> 16;  // RNE
  return (unsigned short)u;
}
__device__ __forceinline__ float bf2f(unsigned short h) {
  return __uint_as_float(((unsigned int)h) << 16);
}

// Packed RNE f32x2 -> bf16x2 (v_cvt_pk_bf16_f32 on gfx950); a -> low 16.
__device__ __forceinline__ unsigned int pkbf(float a, float b) {
  __hip_bfloat162 h = __float22bfloat162_rn(make_float2(a, b));
  unsigned int u;
  __builtin_memcpy(&u, &h, sizeof(u));
  return u;
}

// Staging buffers ([256][32] shorts): 16B chunks XOR-swizzled with (r>>1)&3.
// Writes absorb the swizzle in the global fetch column; reads via this helper.
__device__ __forceinline__ const v8s* stgFrag(const unsigned short* buf, int r,
                                              int quad) {
  return (const v8s*)(buf + r * 32 + ((quad ^ ((r >> 1) & 3)) << 3));
}

// sAt addressing: row-major stride 256 shorts, 16B chunks XOR-swizzled by row.
__device__ __forceinline__ int satIdx(int r, int col) {
  return (r << 8) | ((((col >> 3) ^ (r & 7)) << 3) | (col & 7));
}

// Read an 8-float fragment from the fp32 gram slice [256][64] (32B chunks
// rotated by row) and convert to bf16x8.
__device__ __forceinline__ v8s ldFrag64(const float* buf, int r, int cp) {
  const float* p = buf + r * 64 + (((cp + r) & 7) << 3);
  const float4 x0 = ((const float4*)p)[0];
  const float4 x1 = ((const float4*)p)[1];
  unsigned short h[8];
  h[0] = f2bf(x0.x); h[1] = f2bf(x0.y); h[2] = f2bf(x0.z); h[3] = f2bf(x0.w);
  h[4] = f2bf(x1.x); h[5] = f2bf(x1.y); h[6] = f2bf(x1.z); h[7] = f2bf(x1.w);
  return *(v8s*)h;
}

// ---------------------------------------------------------------------------
// Fused setup (ONE launch, 512 threads/block, role by blockIdx):
//  blocks 0..255    : Gram G[n] = laws[n]@laws[n]^T (bf16 out), fp32 laws
//                     staged through LDS via gl2lds, 64-wide K chunks.
//  blocks 256..1279 : contracts fp32->bf16 (8 rows each) + row norms.
//  blocks 1280..2303: laws fp32->bf16 (4096 elements each).
// ---------------------------------------------------------------------------
__global__ __launch_bounds__(512) void setup_kernel(
    const float* __restrict__ con, const float* __restrict__ laws,
    unsigned short* __restrict__ lawsB, unsigned short* __restrict__ conB,
    float* __restrict__ cnorm, unsigned short* __restrict__ G) {
  const int bid = blockIdx.x;
  const int t = threadIdx.x;
  if (bid < 256) {
    __shared__ float slice[256 * 64];  // 64 KB fp32, row-rotated 32B chunks
    const int n = bid >> 3;
    const int m0 = (bid & 7) << 5;  // 32-row output stripe
    const int lane = t & 63;
    const int w = t >> 6;
    const int quad = lane >> 4;
    const int l16 = lane & 15;
    const int rg = w >> 2;  // 0..1
    const int cg = w & 3;   // 0..3
    const float* lawN = laws + n * (LN * DN);

    v4f acc[4];
#pragma unroll
    for (int b = 0; b < 4; ++b) acc[b] = (v4f){0.f, 0.f, 0.f, 0.f};

    for (int ch = 0; ch < 8; ++ch) {
      const int dk = ch << 6;
      __syncthreads();
#pragma unroll
      for (int i = 0; i < 8; ++i) {
        const int s = i * 512 + t;
        const int row = s >> 4;
        const int p = s & 15;
        const int srcCol = ((((p >> 1) - row) & 7) << 3) + ((p & 1) << 2);
        gl2lds16(lawN + row * DN + dk + srcCol, (char*)slice + s * 16);
      }
      __syncthreads();
#pragma unroll
      for (int step = 0; step < 2; ++step) {
        const int cp = quad + (step << 2);
        v8s af = ldFrag64(slice, m0 + rg * 16 + l16, cp);
#pragma unroll
        for (int ct = 0; ct < 4; ++ct) {
          v8s bf = ldFrag64(slice, cg * 64 + ct * 16 + l16, cp);
          acc[ct] = __builtin_amdgcn_mfma_f32_16x16x32_bf16(af, bf, acc[ct], 0, 0, 0);
        }
      }
    }
    unsigned short* g = G + n * (LN * LN);
#pragma unroll
    for (int ct = 0; ct < 4; ++ct)
#pragma unroll
      for (int reg = 0; reg < 4; ++reg) {
        const int l = m0 + rg * 16 + quad * 4 + reg;
        g[l * LN + cg * 64 + ct * 16 + l16] = f2bf(acc[ct][reg]);
      }
  } else if (bid < 1280) {
    const int r = (bid - 256) * 8 + (t >> 6);
    const int lane = t & 63;
    const float4* src = (const float4*)(con + r * DN + lane * 8);
    float4 x0 = src[0], x1 = src[1];
    unsigned short h[8];
    h[0] = f2bf(x0.x); h[1] = f2bf(x0.y); h[2] = f2bf(x0.z); h[3] = f2bf(x0.w);
    h[4] = f2bf(x1.x); h[5] = f2bf(x1.y); h[6] = f2bf(x1.z); h[7] = f2bf(x1.w);
    *(v8s*)(conB + r * DN + lane * 8) = *(v8s*)h;
    float s = x0.x * x0.x + x0.y * x0.y + x0.z * x0.z + x0.w * x0.w +
              x1.x * x1.x + x1.y * x1.y + x1.z * x1.z + x1.w * x1.w;
#pragma unroll
    for (int m = 1; m < 64; m <<= 1) s += __shfl_xor(s, m, 64);
    if (lane == 0) cnorm[r] = sqrtf(s);
  } else {
    const int off = (bid - 1280) * 4096 + t * 8;
    const float4* src = (const float4*)(laws + off);
    float4 x0 = src[0], x1 = src[1];
    unsigned short h[8];
    h[0] = f2bf(x0.x); h[1] = f2bf(x0.y); h[2] = f2bf(x0.z); h[3] = f2bf(x0.w);
    h[4] = f2bf(x1.x); h[5] = f2bf(x1.y); h[6] = f2bf(x1.z); h[7] = f2bf(x1.w);
    *(v8s*)(lawsB + off) = *(v8s*)h;
  }
}

// ---------------------------------------------------------------------------
// Main: one block per (n,c), 512 threads (8 waves). R12 structure + 3 micro
// changes: (1) phase-A waves with all 32 l-rows >= len skip only the
// B-read+MFMA block (wave-uniform branch; A-frag loads & staging kept) and
// write zeros to their sAt columns so all downstream reads match R12;
// (2) G chunk-0 staging hoisted above softmax (hidden under its VALU);
// (3) packed v_cvt_pk_bf16_f32 sAt pack + streaming softmax (no v/lv arrays).
// ---------------------------------------------------------------------------
__global__ __launch_bounds__(512, 2) void main_kernel(
    const int* __restrict__ law_lens, const unsigned short* __restrict__ lawsB,
    const unsigned short* __restrict__ conB, const unsigned short* __restrict__ Gm,
    const float* __restrict__ cnorm, float* __restrict__ out) {
  extern __shared__ char smem[];
  unsigned short* sAt = (unsigned short*)smem;  // [256][256] swizzled
  char* stage = smem + STAGE_OFF;               // 2 x 16K buffers

  const int bid = blockIdx.x;
  const int n = bid >> 5;  // 32 consecutive blocks share one n
  const int c = bid & 31;
  const int t = threadIdx.x;
  const int lane = t & 63;
  const int w = t >> 6;  // wave 0..7
  const int quad = lane >> 4;
  const int l16 = lane & 15;
  const int sub = t & 3;
  const int rQ = t >> 2;                   // 0..127
  const int subx = sub ^ ((rQ >> 1) & 3);  // swizzled source chunk
  const int len = law_lens[n];
  const int nCh = (len + 31) >> 5;         // phase-B k-chunks (block-uniform)
  const bool active = (w * 32) < len;      // wave has live l-rows in phase A

  const unsigned short* lawN = lawsB + n * (LN * DN);
  const unsigned short* conC = conB + c * (RN * DN);
  const unsigned short* Gn = Gm + n * (LN * LN);

  float w12p[16];
#pragma unroll
  for (int i = 0; i < 16; ++i) w12p[i] = 0.f;

  // ---------------- Phase A ----------------
  {
    const unsigned short* a0p = lawN + (w * 32 + l16) * DN + quad * 8;
    const unsigned short* a1p = a0p + 16 * DN;

    v4f acc[2][16];
#pragma unroll
    for (int a = 0; a < 2; ++a)
#pragma unroll
      for (int b = 0; b < 16; ++b) acc[a][b] = (v4f){0.f, 0.f, 0.f, 0.f};

    // Prologue: stage con chunk 0 into buf0.
#pragma unroll
    for (int i = 0; i < 2; ++i)
      gl2lds16(conC + (i * 128 + rQ) * DN + subx * 8,
               stage + i * 8192 + t * 16);

    for (int ch = 0; ch < 16; ++ch) {
      const int dk = ch << 5;
      __syncthreads();  // drains chunk-ch staging (in flight since iter ch-1)
      // A-frags FIRST (older than prefetch -> auto-wait becomes vmcnt(2)).
      v8s af0 = *(const v8s*)(a0p + dk);
      v8s af1 = *(const v8s*)(a1p + dk);
      __builtin_amdgcn_sched_barrier(0);
      if (ch < 15) {  // prefetch chunk ch+1 into the other buffer
        char* dst = stage + ((ch + 1) & 1) * 16384;
#pragma unroll
        for (int i = 0; i < 2; ++i)
          gl2lds16(conC + (i * 128 + rQ) * DN + (dk + 32) + subx * 8,
                   dst + i * 8192 + t * 16);
      }
      __builtin_amdgcn_sched_barrier(0);
      if (active) {  // wave-uniform: inactive waves produce only zeros below
        const unsigned short* cs =
            (const unsigned short*)(stage + (ch & 1) * 16384);
#pragma unroll
        for (int rt = 0; rt < 16; ++rt) {
          v8s bf = *stgFrag(cs, rt * 16 + l16, quad);
          acc[0][rt] = __builtin_amdgcn_mfma_f32_16x16x32_bf16(af0, bf, acc[0][rt], 0, 0, 0);
          acc[1][rt] = __builtin_amdgcn_mfma_f32_16x16x32_bf16(af1, bf, acc[1][rt], 0, 0, 0);
        }
      }
    }

    __syncthreads();  // all staging reads done; stage buf0 reusable

    // Hoisted: stage G chunk 0 into buf0 NOW -- its latency hides under the
    // softmax VALU below; phase B's first barrier drains it.
#pragma unroll
    for (int i = 0; i < 2; ++i)
      gl2lds16(Gn + (i * 128 + rQ) * LN + subx * 8, stage + i * 8192 + t * 16);

    if (active) {
      // Softmax row ops (streaming; |lv*inv| <= 1 so exp needs no max-sub).
      // Row l lives in 16 lanes (C layout col=lane&15 -> r index). 4 regs =
      // 4 consecutive sAt columns -> packed cvt + b64 writes.
#pragma unroll
      for (int tl = 0; tl < 2; ++tl) {
        unsigned int pk[16][2];
        float a0s[16];
#pragma unroll
        for (int reg = 0; reg < 4; ++reg) {
          const int lg = w * 32 + tl * 16 + quad * 4 + reg;
          float ss = 0.f;
#pragma unroll
          for (int rt = 0; rt < 16; ++rt) {
            const float v = acc[tl][rt][reg] * 0.04419417382415922f;
            const float lv = v > 0.f ? v : 0.1f * v;
            ss += lv * lv;
          }
#pragma unroll
          for (int m = 1; m < 16; m <<= 1) ss += __shfl_xor(ss, m, 64);
          const float inv = 1.f / (sqrtf(ss) + 1e-8f);
          float e[16];
          float den = 0.f;
#pragma unroll
          for (int rt = 0; rt < 16; ++rt) {
            const float v = acc[tl][rt][reg] * 0.04419417382415922f;
            const float lv = v > 0.f ? v : 0.1f * v;
            e[rt] = __expf(lv * inv);
            den += e[rt];
          }
#pragma unroll
          for (int m = 1; m < 16; m <<= 1) den += __shfl_xor(den, m, 64);
          const float sc = (lg < len) ? 4.f / den : 0.f;  // SMOOTH, masked
#pragma unroll
          for (int rt = 0; rt < 16; ++rt) {
            const float v = acc[tl][rt][reg] * 0.04419417382415922f;
            const float a = e[rt] * sc;
            w12p[rt] += a * v;  // raw S -> cosine numerator
            if (reg & 1)
              pk[rt][reg >> 1] = pkbf(a0s[rt], a);
            else
              a0s[rt] = a;
          }
        }
        const int lg0 = w * 32 + tl * 16 + quad * 4;
#pragma unroll
        for (int rt = 0; rt < 16; ++rt)
          *(uint2*)(sAt + satIdx(rt * 16 + l16, lg0)) = *(uint2*)pk[rt];
      }
    } else {
      // Zero this wave's sAt columns so nsq's full-width reads see exact
      // zeros (attn == 0 beyond len) -- matches R12 behavior bit-for-bit.
      uint2 z;
      z.x = 0u;
      z.y = 0u;
#pragma unroll
      for (int tl = 0; tl < 2; ++tl) {
        const int lg0 = w * 32 + tl * 16 + quad * 4;
#pragma unroll
        for (int rt = 0; rt < 16; ++rt)
          *(uint2*)(sAt + satIdx(rt * 16 + l16, lg0)) = z;
      }
    }
  }

  // Reduce w12 partials across quads; keep in registers through phase B.
  // (Inactive waves contribute zeros.)
#pragma unroll
  for (int rt = 0; rt < 16; ++rt) {
    w12p[rt] += __shfl_xor(w12p[rt], 16, 64);
    w12p[rt] += __shfl_xor(w12p[rt], 32, 64);
  }

  // ---------------- Phase B (k capped at nCh = ceil(len/32)) ----------------
  float nsv[2][4];
  {
    v4f acc[2][16];
#pragma unroll
    for (int a = 0; a < 2; ++a)
#pragma unroll
      for (int b = 0; b < 16; ++b) acc[a][b] = (v4f){0.f, 0.f, 0.f, 0.f};

    for (int ch = 0; ch < nCh; ++ch) {
      const int lk = ch << 5;
      __syncthreads();  // drains chunk-ch Gs staging; ch0 also orders sAt
      v8s af0 = *(const v8s*)(sAt + satIdx(w * 32 + l16, lk + quad * 8));
      v8s af1 = *(const v8s*)(sAt + satIdx(w * 32 + 16 + l16, lk + quad * 8));
      __builtin_amdgcn_sched_barrier(0);
      if (ch < nCh - 1) {  // prefetch chunk ch+1
        char* dst = stage + ((ch + 1) & 1) * 16384;
#pragma unroll
        for (int i = 0; i < 2; ++i)
          gl2lds16(Gn + (i * 128 + rQ) * LN + (lk + 32) + subx * 8,
                   dst + i * 8192 + t * 16);
      }
      __builtin_amdgcn_sched_barrier(0);
      const unsigned short* gs =
          (const unsigned short*)(stage + (ch & 1) * 16384);
#pragma unroll
      for (int lt = 0; lt < 16; ++lt) {
        v8s bf = *stgFrag(gs, lt * 16 + l16, quad);  // G row (symmetric)
        acc[0][lt] = __builtin_amdgcn_mfma_f32_16x16x32_bf16(af0, bf, acc[0][lt], 0, 0, 0);
        acc[1][lt] = __builtin_amdgcn_mfma_f32_16x16x32_bf16(af1, bf, acc[1][lt], 0, 0, 0);
      }
    }
    // nsq[r] = sum_l At[r,l] * U[r,l] (sAt cols >= len are exact zeros)
#pragma unroll
    for (int tl = 0; tl < 2; ++tl) {
#pragma unroll
      for (int reg = 0; reg < 4; ++reg) {
        const int r = w * 32 + tl * 16 + quad * 4 + reg;
        float s = 0.f;
#pragma unroll
        for (int lt = 0; lt < 16; ++lt)
          s += acc[tl][lt][reg] * bf2f(sAt[satIdx(r, lt * 16 + l16)]);
#pragma unroll
        for (int m = 1; m < 16; m <<= 1) s += __shfl_xor(s, m, 64);
        nsv[tl][reg] = s;
      }
    }
  }

  // ---------------- Phase C (reductions overlay the stage region) ----------
  float* w12s = (float*)stage;           // [8][256] = 8K
  float* nsqS = (float*)(stage + 8192);  // [256]    = 1K
  float* red = (float*)(stage + 9216);   // [8]
  __syncthreads();  // all Gs reads done; stage is free for reductions
  if (l16 == 0) {
#pragma unroll
    for (int tl = 0; tl < 2; ++tl)
#pragma unroll
      for (int reg = 0; reg < 4; ++reg)
        nsqS[w * 32 + tl * 16 + quad * 4 + reg] = nsv[tl][reg];
  }
  if (lane < 16) {
#pragma unroll
    for (int rt = 0; rt < 16; ++rt) w12s[w * 256 + rt * 16 + lane] = w12p[rt];
  }
  __syncthreads();
  float p = 0.f;
  if (t < 256) {
    float w12 = 0.f;
#pragma unroll
    for (int i = 0; i < 8; ++i) w12 += w12s[i * 256 + t];
    const float w1 = cnorm[c * RN + t];
    const float w2 = sqrtf(fmaxf(nsqS[t], 0.f));
    const float sim = (w12 * 22.627416997969522f) / fmaxf(w1 * w2, 1e-8f);
    p = __expf(6.f * sim);
  }
#pragma unroll
  for (int m = 1; m < 64; m <<= 1) p += __shfl_xor(p, m, 64);
  if (lane == 0) red[w] = p;
  __syncthreads();
  if (t == 0) {
    float s = 0.f;
#pragma unroll
    for (int i = 0; i < 8; ++i) s += red[i];
    out[c * NN + n] = logf(s) / 6.f;
  }
}

// ---------------------------------------------------------------------------
extern "C" void kernel_launch(void* const* d_in, const int* in_sizes, int n_in,
                              void* d_out, int out_size, void* d_ws, size_t ws_size,
                              hipStream_t stream) {
  (void)in_sizes; (void)n_in; (void)out_size;
  const float* contracts = (const float*)d_in[0];
  const float* laws = (const float*)d_in[1];
  const int* law_lens = (const int*)d_in[2];
  float* out = (float*)d_out;

  // Workspace layout (21,004,288 B total)
  unsigned short* lawsB = (unsigned short*)d_ws;  // 8 MiB
  unsigned short* conB = lawsB + NN * LN * DN;    // 8 MiB
  unsigned short* G = conB + CN * RN * DN;        // 4 MiB
  float* cnorm = (float*)(G + NN * LN * LN);      // 32 KiB
  if (ws_size < (size_t)21004288) return;

  hipFuncSetAttribute((const void*)main_kernel,
                      hipFuncAttributeMaxDynamicSharedMemorySize, SMEM_TOTAL);

  // 256 gram + 1024 contracts-prep + 1024 laws-prep blocks, one launch.
  setup_kernel<<<2304, 512, 0, stream>>>(contracts, laws, lawsB, conB, cnorm,
                                         G);
  main_kernel<<<1024, 512, SMEM_TOTAL, stream>>>(law_lens, lawsB, conB, G,
                                                 cnorm, out);
}